// Round 4
// baseline (13335.706 us; speedup 1.0000x reference)
//
#include <hip/hip_runtime.h>
#include <hip/hip_bf16.h>

typedef __hip_bfloat16 bf16;
typedef __attribute__((ext_vector_type(8))) short short8;
typedef __attribute__((ext_vector_type(4))) float f32x4;

#define N_ 8
#define B_ 64
#define T_ 256
#define IN_ 64
#define H_ 512
#define G4_ 2048
#define M_ 512
#define O_ 7

__device__ __forceinline__ float sigf(float x) { return 1.0f / (1.0f + __expf(-x)); }
__device__ __forceinline__ float tanhfast(float x) { return 2.0f / (1.0f + __expf(-2.0f * x)) - 1.0f; }

// ---------------- convert fp32 -> bf16 (grid-stride over float4 groups) ----------------
__global__ void cvt_kernel(const float* __restrict__ src, bf16* __restrict__ dst, int n4) {
  for (int i = blockIdx.x * blockDim.x + threadIdx.x; i < n4; i += gridDim.x * blockDim.x) {
    float4 v = ((const float4*)src)[i];
    bf16 t0 = __float2bfloat16(v.x), t1 = __float2bfloat16(v.y);
    bf16 t2 = __float2bfloat16(v.z), t3 = __float2bfloat16(v.w);
    ushort4 o;
    o.x = *(unsigned short*)&t0; o.y = *(unsigned short*)&t1;
    o.z = *(unsigned short*)&t2; o.w = *(unsigned short*)&t3;
    ((ushort4*)dst)[i] = o;
  }
}

// ---------------- K1: z[t][b][h] = leaky(x@Win^T + bin, 0.2)*10  (fp32 in, bf16 out) ----------------
__global__ void input_kernel(const float* __restrict__ x, const float* __restrict__ Win,
                             const float* __restrict__ bin, bf16* __restrict__ z) {
  int bid = blockIdx.x;
  int t = bid >> 6;
  int b = bid & 63;
  __shared__ float xr[IN_];
  int tid = threadIdx.x;
  if (tid < IN_) xr[tid] = x[((size_t)b * T_ + t) * IN_ + tid];
  __syncthreads();
  for (int h = tid; h < H_; h += 256) {
    const float* w = Win + (size_t)h * IN_;
    float s = bin[h];
#pragma unroll 16
    for (int i = 0; i < IN_; ++i) s += xr[i] * w[i];
    s = (s > 0.f ? s : 0.2f * s) * 10.f;
    z[((size_t)t * B_ + b) * H_ + h] = __float2bfloat16(s);
  }
}

// ---------------- K2: one pipeline super-step per launch ----------------
// 256 blocks x 512 thr. Block (n, ub): 16 hidden/M units of model n.
// Stage s: L0(t=s), L1(t=s-1), H1(t=s-2), H2(t=s-3). Kernel boundary = sync.
// All cross-stage data flows through previous launches (parity-disjoint slices).
__global__ void __launch_bounds__(512, 1) step_kernel(
    const int s,
    const bf16* __restrict__ z,
    const bf16* __restrict__ Wih0, const bf16* __restrict__ Whh0,
    const float* __restrict__ bih0, const float* __restrict__ bhh0,
    const bf16* __restrict__ Wih1, const bf16* __restrict__ Whh1,
    const float* __restrict__ bih1, const float* __restrict__ bhh1,
    const bf16* __restrict__ Wh1, const float* __restrict__ bh1,
    const float* __restrict__ Wh2, const float* __restrict__ bh2,
    bf16* __restrict__ h0buf, bf16* __restrict__ h1buf,
    bf16* __restrict__ mstage, float* __restrict__ out,
    float* __restrict__ c0g, float* __restrict__ c1g)
{
  __shared__ float S0[4][B_][16];
  __shared__ float S1[4][B_][16];

  const int tid = threadIdx.x;
  const int lane = tid & 63;
  const int wv = tid >> 6;   // 0..7
  const int rs = wv & 3;     // row strip (16 rows of B=64)
  const int gp = wv >> 2;    // gate pair: 0 -> (i,f), 1 -> (g,o)
  const int q = lane >> 4;
  const int cl = lane & 15;
  const int bid = blockIdx.x;
  const int n = bid >> 5;
  const int blk = bid & 31;
  const int ub = blk << 4;
  const int g0 = gp * 2, g1 = g0 + 1;

  const bool doL0 = (s < T_);
  const bool doL1 = (s >= 1 && s <= T_);
  const bool doH1 = (s >= 2 && s <= T_ + 1);
  const bool doH2 = (s >= 3);

  const size_t NBH = (size_t)N_ * B_ * H_;
  const size_t NBM = (size_t)N_ * B_ * M_;
  const bf16* W_A1 = Wih0 + (size_t)n * G4_ * H_;
  const bf16* W_A2 = Whh0 + (size_t)n * G4_ * H_;
  const bf16* W_B1 = Whh1 + (size_t)n * G4_ * H_;
  const bf16* W_B2 = Wih1 + (size_t)n * G4_ * H_;
  const size_t wr0 = (size_t)(g0 * H_ + ub + cl) * H_ + q * 8;
  const size_t wr1 = (size_t)(g1 * H_ + ub + cl) * H_ + q * 8;
  const int arow = (rs * 16 + cl) * H_ + q * 8;

  const float bA0 = bih0[n * G4_ + g0 * H_ + ub + cl] + bhh0[n * G4_ + g0 * H_ + ub + cl];
  const float bA1 = bih0[n * G4_ + g1 * H_ + ub + cl] + bhh0[n * G4_ + g1 * H_ + ub + cl];
  const float bB0 = bih1[n * G4_ + g0 * H_ + ub + cl] + bhh1[n * G4_ + g0 * H_ + ub + cl];
  const float bB1 = bih1[n * G4_ + g1 * H_ + ub + cl] + bhh1[n * G4_ + g1 * H_ + ub + cl];

  f32x4 aA0 = (f32x4){bA0, bA0, bA0, bA0};
  f32x4 aA1 = (f32x4){bA1, bA1, bA1, bA1};
  f32x4 aB0 = (f32x4){bB0, bB0, bB0, bB0};
  f32x4 aB1 = (f32x4){bB1, bB1, bB1, bB1};

  if (doL0) {
    const bf16* Az = z + (size_t)s * B_ * H_;
    const bf16* Ah = h0buf + (size_t)((s & 1) ^ 1) * NBH + (size_t)n * B_ * H_;
    for (int kk = 0; kk < H_; kk += 32) {
      short8 a1 = *(const short8*)(Az + arow + kk);
      short8 a2 = *(const short8*)(Ah + arow + kk);
      short8 b10 = *(const short8*)(W_A1 + wr0 + kk);
      short8 b11 = *(const short8*)(W_A1 + wr1 + kk);
      short8 b20 = *(const short8*)(W_A2 + wr0 + kk);
      short8 b21 = *(const short8*)(W_A2 + wr1 + kk);
      aA0 = __builtin_amdgcn_mfma_f32_16x16x32_bf16(a1, b10, aA0, 0, 0, 0);
      aA0 = __builtin_amdgcn_mfma_f32_16x16x32_bf16(a2, b20, aA0, 0, 0, 0);
      aA1 = __builtin_amdgcn_mfma_f32_16x16x32_bf16(a1, b11, aA1, 0, 0, 0);
      aA1 = __builtin_amdgcn_mfma_f32_16x16x32_bf16(a2, b21, aA1, 0, 0, 0);
    }
  }
  if (doL1) {
    const int t = s - 1;
    const bf16* Ah1 = h1buf + (size_t)((t & 1) ^ 1) * NBH + (size_t)n * B_ * H_;
    const bf16* Ah0 = h0buf + (size_t)(t & 1) * NBH + (size_t)n * B_ * H_;
    for (int kk = 0; kk < H_; kk += 32) {
      short8 a1 = *(const short8*)(Ah1 + arow + kk);
      short8 a2 = *(const short8*)(Ah0 + arow + kk);
      short8 b10 = *(const short8*)(W_B1 + wr0 + kk);
      short8 b11 = *(const short8*)(W_B1 + wr1 + kk);
      short8 b20 = *(const short8*)(W_B2 + wr0 + kk);
      short8 b21 = *(const short8*)(W_B2 + wr1 + kk);
      aB0 = __builtin_amdgcn_mfma_f32_16x16x32_bf16(a1, b10, aB0, 0, 0, 0);
      aB0 = __builtin_amdgcn_mfma_f32_16x16x32_bf16(a2, b20, aB0, 0, 0, 0);
      aB1 = __builtin_amdgcn_mfma_f32_16x16x32_bf16(a1, b11, aB1, 0, 0, 0);
      aB1 = __builtin_amdgcn_mfma_f32_16x16x32_bf16(a2, b21, aB1, 0, 0, 0);
    }
  }
  // H1: 16 M-units of leaky(h1(s-2) @ Wh1^T + bh1) for all 64 batches (waves 0..3)
  if (doH1 && wv < 4) {
    const int tH1 = s - 2;
    float bv = bh1[n * M_ + ub + cl];
    f32x4 aH = (f32x4){bv, bv, bv, bv};
    const bf16* hsrc = h1buf + (size_t)(tH1 & 1) * NBH + (size_t)n * B_ * H_;
    const bf16* w1p = Wh1 + (size_t)n * M_ * H_ + (size_t)(ub + cl) * H_ + q * 8;
    const int ar = (wv * 16 + cl) * H_ + q * 8;
    for (int kk = 0; kk < H_; kk += 32) {
      short8 a = *(const short8*)(hsrc + ar + kk);
      short8 b = *(const short8*)(w1p + kk);
      aH = __builtin_amdgcn_mfma_f32_16x16x32_bf16(a, b, aH, 0, 0, 0);
    }
    bf16* msl = mstage + (size_t)(tH1 & 1) * NBM + (size_t)n * B_ * M_;
#pragma unroll
    for (int r = 0; r < 4; ++r) {
      float v = aH[r];
      v = v > 0.f ? v : 0.2f * v;
      msl[(wv * 16 + q * 4 + r) * M_ + ub + cl] = __float2bfloat16(v);
    }
  }
  // H2: 2 batches x 7 outputs, dot over M=512 (waves 0..1); Wh2 read fp32
  if (doH2 && wv < 2) {
    const int tH2 = s - 3;
    const int b = blk * 2 + wv;
    const int o = lane & 7;
    const int oc = o < 7 ? o : 0;
    const int mc = (lane >> 3) * 64;
    const bf16* ms = mstage + (size_t)(tH2 & 1) * NBM + ((size_t)n * B_ + b) * M_ + mc;
    const float* w2p = Wh2 + (size_t)n * O_ * M_ + (size_t)oc * M_ + mc;
    float p = 0.f;
#pragma unroll
    for (int j = 0; j < 64; j += 8) {
      short8 av = *(const short8*)(ms + j);
      const bf16* ae = (const bf16*)&av;
      float4 w0 = *(const float4*)(w2p + j);
      float4 w1 = *(const float4*)(w2p + j + 4);
      p += (float)ae[0] * w0.x + (float)ae[1] * w0.y + (float)ae[2] * w0.z + (float)ae[3] * w0.w
         + (float)ae[4] * w1.x + (float)ae[5] * w1.y + (float)ae[6] * w1.z + (float)ae[7] * w1.w;
    }
    p += __shfl_xor(p, 8, 64);
    p += __shfl_xor(p, 16, 64);
    p += __shfl_xor(p, 32, 64);
    if (lane < 7) {
      p += bh2[n * O_ + o];
      out[(((size_t)n * B_ + b) * T_ + tH2) * O_ + o] = p;
    }
  }

  if (doL0) {
#pragma unroll
    for (int r = 0; r < 4; ++r) {
      S0[g0][rs * 16 + q * 4 + r][cl] = aA0[r];
      S0[g1][rs * 16 + q * 4 + r][cl] = aA1[r];
    }
  }
  if (doL1) {
#pragma unroll
    for (int r = 0; r < 4; ++r) {
      S1[g0][rs * 16 + q * 4 + r][cl] = aB0[r];
      S1[g1][rs * 16 + q * 4 + r][cl] = aB1[r];
    }
  }
  __syncthreads();

  const size_t cbase = (size_t)bid * (B_ * 16);
  if (doL0) {
    bf16* h0out = h0buf + (size_t)(s & 1) * NBH + (size_t)n * B_ * H_;
    for (int e = tid; e < B_ * 16; e += 512) {
      int row = e >> 4, ul = e & 15;
      float gi = S0[0][row][ul], gf = S0[1][row][ul], gg = S0[2][row][ul], go = S0[3][row][ul];
      float c = c0g[cbase + e];
      float cn = sigf(gf) * c + sigf(gi) * tanhfast(gg);
      c0g[cbase + e] = cn;
      h0out[row * H_ + ub + ul] = __float2bfloat16(sigf(go) * tanhfast(cn));
    }
  }
  if (doL1) {
    const int t = s - 1;
    bf16* h1out = h1buf + (size_t)(t & 1) * NBH + (size_t)n * B_ * H_;
    for (int e = tid; e < B_ * 16; e += 512) {
      int row = e >> 4, ul = e & 15;
      float gi = S1[0][row][ul], gf = S1[1][row][ul], gg = S1[2][row][ul], go = S1[3][row][ul];
      float c = c1g[cbase + e];
      float cn = sigf(gf) * c + sigf(gi) * tanhfast(gg);
      c1g[cbase + e] = cn;
      h1out[row * H_ + ub + ul] = __float2bfloat16(sigf(go) * tanhfast(cn));
    }
  }
}

extern "C" void kernel_launch(void* const* d_in, const int* in_sizes, int n_in,
                              void* d_out, int out_size, void* d_ws, size_t ws_size,
                              hipStream_t stream) {
  (void)in_sizes; (void)n_in; (void)out_size; (void)ws_size;
  const float* x    = (const float*)d_in[0];
  const float* Win  = (const float*)d_in[1];
  const float* bin  = (const float*)d_in[2];
  const float* Wih0 = (const float*)d_in[3];
  const float* Whh0 = (const float*)d_in[4];
  const float* bih0 = (const float*)d_in[5];
  const float* bhh0 = (const float*)d_in[6];
  const float* Wih1 = (const float*)d_in[7];
  const float* Whh1 = (const float*)d_in[8];
  const float* bih1 = (const float*)d_in[9];
  const float* bhh1 = (const float*)d_in[10];
  const float* Wh1  = (const float*)d_in[11];
  const float* bh1  = (const float*)d_in[12];
  const float* Wh2  = (const float*)d_in[13];
  const float* bh2  = (const float*)d_in[14];

  const size_t WLSTM = (size_t)N_ * G4_ * H_;          // 8,388,608 elements
  const size_t WH1   = (size_t)N_ * M_ * H_;           // 2,097,152 elements

  char* ws = (char*)d_ws;
  size_t off = 0;
  bf16* z      = (bf16*)(ws + off); off += (size_t)T_ * B_ * H_ * sizeof(bf16);   // 16 MB
  bf16* Wih0b  = (bf16*)(ws + off); off += WLSTM * sizeof(bf16);                  // 16 MB
  bf16* Whh0b  = (bf16*)(ws + off); off += WLSTM * sizeof(bf16);
  bf16* Wih1b  = (bf16*)(ws + off); off += WLSTM * sizeof(bf16);
  bf16* Whh1b  = (bf16*)(ws + off); off += WLSTM * sizeof(bf16);
  bf16* Wh1b   = (bf16*)(ws + off); off += WH1 * sizeof(bf16);                    // 4 MB
  bf16* h0buf  = (bf16*)(ws + off); off += 2 * (size_t)N_ * B_ * H_ * sizeof(bf16);
  bf16* h1buf  = (bf16*)(ws + off); off += 2 * (size_t)N_ * B_ * H_ * sizeof(bf16);
  bf16* mstage = (bf16*)(ws + off); off += 2 * (size_t)N_ * B_ * M_ * sizeof(bf16);
  float* c0g   = (float*)(ws + off); off += (size_t)N_ * B_ * H_ * sizeof(float);
  float* c1g   = (float*)(ws + off); off += (size_t)N_ * B_ * H_ * sizeof(float);

  // zero h/m/c state region (contiguous: h0buf .. c1g end)
  hipMemsetAsync(h0buf, 0, (char*)(c1g + (size_t)N_ * B_ * H_) - (char*)h0buf, stream);

  // one-time fp32 -> bf16 weight conversion
  cvt_kernel<<<dim3(2048), dim3(256), 0, stream>>>(Wih0, Wih0b, (int)(WLSTM / 4));
  cvt_kernel<<<dim3(2048), dim3(256), 0, stream>>>(Whh0, Whh0b, (int)(WLSTM / 4));
  cvt_kernel<<<dim3(2048), dim3(256), 0, stream>>>(Wih1, Wih1b, (int)(WLSTM / 4));
  cvt_kernel<<<dim3(2048), dim3(256), 0, stream>>>(Whh1, Whh1b, (int)(WLSTM / 4));
  cvt_kernel<<<dim3(1024), dim3(256), 0, stream>>>(Wh1, Wh1b, (int)(WH1 / 4));

  input_kernel<<<dim3(T_ * B_), dim3(256), 0, stream>>>(x, Win, bin, z);
  for (int s = 0; s < T_ + 3; ++s) {
    step_kernel<<<dim3(256), dim3(512), 0, stream>>>(
        s, z, Wih0b, Whh0b, bih0, bhh0, Wih1b, Whh1b, bih1, bhh1,
        Wh1b, bh1, Wh2, bh2, h0buf, h1buf, mstage, (float*)d_out, c0g, c1g);
  }
}

// Round 5
// 11941.799 us; speedup vs baseline: 1.1167x; 1.1167x over previous
//
#include <hip/hip_runtime.h>
#include <hip/hip_bf16.h>

typedef __hip_bfloat16 bf16;
typedef __attribute__((ext_vector_type(8))) short short8;
typedef __attribute__((ext_vector_type(4))) float f32x4;

#define N_ 8
#define B_ 64
#define T_ 256
#define IN_ 64
#define H_ 512
#define G4_ 2048
#define M_ 512
#define O_ 7

__device__ __forceinline__ float sigf(float x) { return 1.0f / (1.0f + __expf(-x)); }
__device__ __forceinline__ float tanhfast(float x) { return 2.0f / (1.0f + __expf(-2.0f * x)) - 1.0f; }

// ---------------- convert fp32 -> bf16 ----------------
__global__ void cvt_kernel(const float* __restrict__ src, bf16* __restrict__ dst, int n4) {
  for (int i = blockIdx.x * blockDim.x + threadIdx.x; i < n4; i += gridDim.x * blockDim.x) {
    float4 v = ((const float4*)src)[i];
    bf16 t0 = __float2bfloat16(v.x), t1 = __float2bfloat16(v.y);
    bf16 t2 = __float2bfloat16(v.z), t3 = __float2bfloat16(v.w);
    ushort4 o;
    o.x = *(unsigned short*)&t0; o.y = *(unsigned short*)&t1;
    o.z = *(unsigned short*)&t2; o.w = *(unsigned short*)&t3;
    ((ushort4*)dst)[i] = o;
  }
}

// ---------------- K1: z = leaky(x@Win^T + bin)*10 ----------------
__global__ void input_kernel(const float* __restrict__ x, const float* __restrict__ Win,
                             const float* __restrict__ bin, bf16* __restrict__ z) {
  int bid = blockIdx.x;
  int t = bid >> 6;
  int b = bid & 63;
  __shared__ float xr[IN_];
  int tid = threadIdx.x;
  if (tid < IN_) xr[tid] = x[((size_t)b * T_ + t) * IN_ + tid];
  __syncthreads();
  for (int h = tid; h < H_; h += 256) {
    const float* w = Win + (size_t)h * IN_;
    float s = bin[h];
#pragma unroll 16
    for (int i = 0; i < IN_; ++i) s += xr[i] * w[i];
    s = (s > 0.f ? s : 0.2f * s) * 10.f;
    z[((size_t)t * B_ + b) * H_ + h] = __float2bfloat16(s);
  }
}

// ---------------- per-model grid barrier (32 blocks, monotonic counter) ----------------
__device__ __forceinline__ void gbar(unsigned* ctr, unsigned target) {
  __syncthreads();
  if (threadIdx.x == 0) {
    __hip_atomic_fetch_add(ctr, 1u, __ATOMIC_RELEASE, __HIP_MEMORY_SCOPE_AGENT);
    while (__hip_atomic_load(ctr, __ATOMIC_ACQUIRE, __HIP_MEMORY_SCOPE_AGENT) < target) {
      __builtin_amdgcn_s_sleep(1);
    }
  }
  __syncthreads();
}

// ---------------- K2: persistent weight-stationary LSTM scan + fused head ----------------
// 256 blocks x 512 thr, 1 block/CU. Block (n, ub): 16 hidden/M units of model n.
// Wave w = 2*g + m owns (gate g, matrix m) for BOTH layers; its B-fragments
// (16 units x 512 K, 16 k-chunks) live in 64+64 VGPRs for the whole kernel.
// Superstep s: L0(t=s), L1(t=s-1), H1(t=s-2), H2(t=s-3); per-model barrier each.
__global__ void __launch_bounds__(512, 2) scan_kernel(
    const bf16* __restrict__ z,
    const bf16* __restrict__ Wih0, const bf16* __restrict__ Whh0,
    const float* __restrict__ bih0, const float* __restrict__ bhh0,
    const bf16* __restrict__ Wih1, const bf16* __restrict__ Whh1,
    const float* __restrict__ bih1, const float* __restrict__ bhh1,
    const bf16* __restrict__ Wh1, const float* __restrict__ bh1,
    const float* __restrict__ Wh2, const float* __restrict__ bh2,
    bf16* __restrict__ h0buf, bf16* __restrict__ h1buf,
    bf16* __restrict__ mstage, float* __restrict__ out,
    unsigned* __restrict__ barctr)
{
  __shared__ float S0[8][B_][16];   // 8 wave-slots (gate g: slots 2g + 2g+1)
  __shared__ float S1[8][B_][16];
  __shared__ float c0s[B_ * 16];
  __shared__ float c1s[B_ * 16];

  const int tid = threadIdx.x;
  const int lane = tid & 63;
  const int w = tid >> 6;      // 0..7
  const int m = w & 1;         // 0: ih-matrix, 1: hh-matrix
  const int g = w >> 1;        // gate 0..3 (i,f,g,o)
  const int q = lane >> 4;
  const int cl = lane & 15;
  const int bid = blockIdx.x;
  const int n = bid >> 5;
  const int blk = bid & 31;
  const int ub = blk << 4;

  const size_t NBH = (size_t)N_ * B_ * H_;
  const size_t NBM = (size_t)N_ * B_ * M_;

  // ---- one-time weight preload into registers ----
  const size_t wrow = (size_t)n * G4_ * H_ + (size_t)(g * H_ + ub + cl) * H_ + q * 8;
  const bf16* WL0 = (m == 0 ? Wih0 : Whh0) + wrow;
  const bf16* WL1 = (m == 0 ? Wih1 : Whh1) + wrow;
  short8 wl0[16], wl1[16];
#pragma unroll
  for (int kk = 0; kk < 16; ++kk) {
    wl0[kk] = *(const short8*)(WL0 + kk * 32);
    wl1[kk] = *(const short8*)(WL1 + kk * 32);
  }
  // bias carried by the m==0 wave of each gate
  const int bi = n * G4_ + g * H_ + ub + cl;
  const float bs0 = (m == 0) ? (bih0[bi] + bhh0[bi]) : 0.f;
  const float bs1 = (m == 0) ? (bih1[bi] + bhh1[bi]) : 0.f;
  const float bh1v = bh1[n * M_ + ub + cl];   // H1 bias (waves 0..3 use it)

  for (int e = tid; e < B_ * 16; e += 512) { c0s[e] = 0.f; c1s[e] = 0.f; }

  unsigned* ctr = barctr + n * 32;
  unsigned target = 0;

  for (int s = 0; s < T_ + 3; ++s) {
    const bool doL0 = (s < T_);
    const bool doL1 = (s >= 1 && s <= T_);
    const bool doH1 = (s >= 2 && s <= T_ + 1);
    const bool doH2 = (s >= 3);

    // ---- L0 MFMA: this wave's (matrix,gate) partial over 4 batch strips ----
    if (doL0) {
      const bf16* A = (m == 0)
          ? z + (size_t)s * B_ * H_
          : h0buf + (size_t)((s & 1) ^ 1) * NBH + (size_t)n * B_ * H_;
#pragma unroll
      for (int strip = 0; strip < 4; ++strip) {
        f32x4 acc = (f32x4){bs0, bs0, bs0, bs0};
        const bf16* Ap = A + (size_t)(strip * 16 + cl) * H_ + q * 8;
#pragma unroll
        for (int kk = 0; kk < 16; ++kk) {
          short8 a = *(const short8*)(Ap + kk * 32);
          acc = __builtin_amdgcn_mfma_f32_16x16x32_bf16(a, wl0[kk], acc, 0, 0, 0);
        }
#pragma unroll
        for (int r = 0; r < 4; ++r) S0[w][strip * 16 + q * 4 + r][cl] = acc[r];
      }
    }
    // ---- L1 MFMA ----
    if (doL1) {
      const int t = s - 1;
      const bf16* A = (m == 0)
          ? h0buf + (size_t)(t & 1) * NBH + (size_t)n * B_ * H_
          : h1buf + (size_t)((t & 1) ^ 1) * NBH + (size_t)n * B_ * H_;
#pragma unroll
      for (int strip = 0; strip < 4; ++strip) {
        f32x4 acc = (f32x4){bs1, bs1, bs1, bs1};
        const bf16* Ap = A + (size_t)(strip * 16 + cl) * H_ + q * 8;
#pragma unroll
        for (int kk = 0; kk < 16; ++kk) {
          short8 a = *(const short8*)(Ap + kk * 32);
          acc = __builtin_amdgcn_mfma_f32_16x16x32_bf16(a, wl1[kk], acc, 0, 0, 0);
        }
#pragma unroll
        for (int r = 0; r < 4; ++r) S1[w][strip * 16 + q * 4 + r][cl] = acc[r];
      }
    }
    // ---- H1: 16 M-units of leaky(h1(s-2)@Wh1^T + bh1), all 64 batches (waves 0..3) ----
    if (doH1 && w < 4) {
      const int tH1 = s - 2;
      f32x4 aH = (f32x4){bh1v, bh1v, bh1v, bh1v};
      const bf16* hsrc = h1buf + (size_t)(tH1 & 1) * NBH + (size_t)n * B_ * H_;
      const bf16* w1p = Wh1 + (size_t)n * M_ * H_ + (size_t)(ub + cl) * H_ + q * 8;
      const int ar = (w * 16 + cl) * H_ + q * 8;
      for (int kk = 0; kk < H_; kk += 32) {
        short8 a = *(const short8*)(hsrc + ar + kk);
        short8 b = *(const short8*)(w1p + kk);
        aH = __builtin_amdgcn_mfma_f32_16x16x32_bf16(a, b, aH, 0, 0, 0);
      }
      bf16* msl = mstage + (size_t)(tH1 & 1) * NBM + (size_t)n * B_ * M_;
#pragma unroll
      for (int r = 0; r < 4; ++r) {
        float v = aH[r];
        v = v > 0.f ? v : 0.2f * v;
        msl[(w * 16 + q * 4 + r) * M_ + ub + cl] = __float2bfloat16(v);
      }
    }
    // ---- H2: 2 batches x 7 outputs, dot over M=512 (waves 0..1) ----
    if (doH2 && w < 2) {
      const int tH2 = s - 3;
      const int b = blk * 2 + w;
      const int o = lane & 7;
      const int oc = o < 7 ? o : 0;
      const int mc = (lane >> 3) * 64;
      const bf16* ms = mstage + (size_t)(tH2 & 1) * NBM + ((size_t)n * B_ + b) * M_ + mc;
      const float* w2p = Wh2 + (size_t)n * O_ * M_ + (size_t)oc * M_ + mc;
      float p = 0.f;
#pragma unroll
      for (int j = 0; j < 64; j += 8) {
        short8 av = *(const short8*)(ms + j);
        const bf16* ae = (const bf16*)&av;
        float4 w0 = *(const float4*)(w2p + j);
        float4 w1 = *(const float4*)(w2p + j + 4);
        p += (float)ae[0] * w0.x + (float)ae[1] * w0.y + (float)ae[2] * w0.z + (float)ae[3] * w0.w
           + (float)ae[4] * w1.x + (float)ae[5] * w1.y + (float)ae[6] * w1.z + (float)ae[7] * w1.w;
      }
      p += __shfl_xor(p, 8, 64);
      p += __shfl_xor(p, 16, 64);
      p += __shfl_xor(p, 32, 64);
      if (lane < 7) {
        p += bh2[n * O_ + o];
        out[(((size_t)n * B_ + b) * T_ + tH2) * O_ + o] = p;
      }
    }

    __syncthreads();

    // ---- elementwise: assemble gates (sum ih+hh slots), update c, write h ----
    if (doL0) {
      bf16* h0out = h0buf + (size_t)(s & 1) * NBH + (size_t)n * B_ * H_;
      for (int e = tid; e < B_ * 16; e += 512) {
        int row = e >> 4, ul = e & 15;
        float gi = S0[0][row][ul] + S0[1][row][ul];
        float gf = S0[2][row][ul] + S0[3][row][ul];
        float gg = S0[4][row][ul] + S0[5][row][ul];
        float go = S0[6][row][ul] + S0[7][row][ul];
        float c = c0s[e];
        float cn = sigf(gf) * c + sigf(gi) * tanhfast(gg);
        c0s[e] = cn;
        h0out[row * H_ + ub + ul] = __float2bfloat16(sigf(go) * tanhfast(cn));
      }
    }
    if (doL1) {
      const int t = s - 1;
      bf16* h1out = h1buf + (size_t)(t & 1) * NBH + (size_t)n * B_ * H_;
      for (int e = tid; e < B_ * 16; e += 512) {
        int row = e >> 4, ul = e & 15;
        float gi = S1[0][row][ul] + S1[1][row][ul];
        float gf = S1[2][row][ul] + S1[3][row][ul];
        float gg = S1[4][row][ul] + S1[5][row][ul];
        float go = S1[6][row][ul] + S1[7][row][ul];
        float c = c1s[e];
        float cn = sigf(gf) * c + sigf(gi) * tanhfast(gg);
        c1s[e] = cn;
        h1out[row * H_ + ub + ul] = __float2bfloat16(sigf(go) * tanhfast(cn));
      }
    }

    target += 32;
    gbar(ctr, target);
  }
}

extern "C" void kernel_launch(void* const* d_in, const int* in_sizes, int n_in,
                              void* d_out, int out_size, void* d_ws, size_t ws_size,
                              hipStream_t stream) {
  (void)in_sizes; (void)n_in; (void)out_size; (void)ws_size;
  const float* x    = (const float*)d_in[0];
  const float* Win  = (const float*)d_in[1];
  const float* bin  = (const float*)d_in[2];
  const float* Wih0 = (const float*)d_in[3];
  const float* Whh0 = (const float*)d_in[4];
  const float* bih0 = (const float*)d_in[5];
  const float* bhh0 = (const float*)d_in[6];
  const float* Wih1 = (const float*)d_in[7];
  const float* Whh1 = (const float*)d_in[8];
  const float* bih1 = (const float*)d_in[9];
  const float* bhh1 = (const float*)d_in[10];
  const float* Wh1  = (const float*)d_in[11];
  const float* bh1  = (const float*)d_in[12];
  const float* Wh2  = (const float*)d_in[13];
  const float* bh2  = (const float*)d_in[14];

  const size_t WLSTM = (size_t)N_ * G4_ * H_;
  const size_t WH1   = (size_t)N_ * M_ * H_;

  char* ws = (char*)d_ws;
  size_t off = 0;
  bf16* z      = (bf16*)(ws + off); off += (size_t)T_ * B_ * H_ * sizeof(bf16);
  bf16* Wih0b  = (bf16*)(ws + off); off += WLSTM * sizeof(bf16);
  bf16* Whh0b  = (bf16*)(ws + off); off += WLSTM * sizeof(bf16);
  bf16* Wih1b  = (bf16*)(ws + off); off += WLSTM * sizeof(bf16);
  bf16* Whh1b  = (bf16*)(ws + off); off += WLSTM * sizeof(bf16);
  bf16* Wh1b   = (bf16*)(ws + off); off += WH1 * sizeof(bf16);
  bf16* h0buf  = (bf16*)(ws + off); off += 2 * (size_t)N_ * B_ * H_ * sizeof(bf16);
  bf16* h1buf  = (bf16*)(ws + off); off += 2 * (size_t)N_ * B_ * H_ * sizeof(bf16);
  bf16* mstage = (bf16*)(ws + off); off += 2 * (size_t)N_ * B_ * M_ * sizeof(bf16);
  unsigned* barctr = (unsigned*)(ws + off); off += 8 * 32 * sizeof(unsigned);

  // zero h/m state + barrier counters (contiguous span)
  hipMemsetAsync(h0buf, 0, (char*)(barctr + 8 * 32) - (char*)h0buf, stream);

  cvt_kernel<<<dim3(2048), dim3(256), 0, stream>>>(Wih0, Wih0b, (int)(WLSTM / 4));
  cvt_kernel<<<dim3(2048), dim3(256), 0, stream>>>(Whh0, Whh0b, (int)(WLSTM / 4));
  cvt_kernel<<<dim3(2048), dim3(256), 0, stream>>>(Wih1, Wih1b, (int)(WLSTM / 4));
  cvt_kernel<<<dim3(2048), dim3(256), 0, stream>>>(Whh1, Whh1b, (int)(WLSTM / 4));
  cvt_kernel<<<dim3(1024), dim3(256), 0, stream>>>(Wh1, Wh1b, (int)(WH1 / 4));

  input_kernel<<<dim3(T_ * B_), dim3(256), 0, stream>>>(x, Win, bin, z);

  scan_kernel<<<dim3(256), dim3(512), 0, stream>>>(
      z, Wih0b, Whh0b, bih0, bhh0, Wih1b, Whh1b, bih1, bhh1,
      Wh1b, bh1, Wh2, bh2, h0buf, h1buf, mstage, (float*)d_out, barctr);
}